// Round 11
// baseline (758.065 us; speedup 1.0000x reference)
//
#include <hip/hip_runtime.h>
#include <hip/hip_bf16.h>

// FraudSNN fused kernel: GEMM (bf16 MFMA) + LIF recurrence, T=10, F=256, H=512.
// R11: delete the xt LDS staging entirely — each x element feeds exactly one A-fragment,
// so load A-frags straight from global (fully coalesced at 64B granule, immediate offsets)
// and cvt fp32->bf16 in-register. LDS = mem1 (128 KB, 0-conflict) + double-buffered red.
// ONE barrier per t (was 4). Persistent live regs ~56 < the compiler's immovable 64 budget.

typedef short short8 __attribute__((ext_vector_type(8)));
typedef float f32x4 __attribute__((ext_vector_type(4)));

__device__ __forceinline__ unsigned short bfbits(float f) {
  union { __hip_bfloat16 h; unsigned short u; } c;
  c.h = __float2bfloat16(f);   // hardware RNE
  return c.u;
}

__device__ __forceinline__ unsigned int bfpack(float a, float b) {
  return (unsigned int)bfbits(a) | ((unsigned int)bfbits(b) << 16);
}

__device__ __forceinline__ float fast_sigmoid(float z) {
  float e = __expf(-z);
  return __builtin_amdgcn_rcpf(1.0f + e);
}

__global__ void w1_to_bf16(const float* __restrict__ w1, unsigned short* __restrict__ o) {
  int i = blockIdx.x * 256 + threadIdx.x;      // 32768 float4s = 131072 floats
  float4 v = reinterpret_cast<const float4*>(w1)[i];
  reinterpret_cast<uint2*>(o)[i] = make_uint2(bfpack(v.x, v.y), bfpack(v.z, v.w));
}

__device__ __forceinline__ short8 load_a_frag(const float* p) {
  const float4 v0 = *reinterpret_cast<const float4*>(p);
  const float4 v1 = *reinterpret_cast<const float4*>(p + 4);
  union { unsigned int u[4]; short8 s; } cv;
  cv.u[0] = bfpack(v0.x, v0.y);
  cv.u[1] = bfpack(v0.z, v0.w);
  cv.u[2] = bfpack(v1.x, v1.y);
  cv.u[3] = bfpack(v1.z, v1.w);
  return cv.s;
}

// 1024 threads = 16 waves. Block: 64 batch rows; wave w owns 64 rows x h in [w*32, w*32+32).
template <bool USE_WS>
__global__
__attribute__((amdgpu_flat_work_group_size(1024, 1024)))
void snn_main(const float* __restrict__ x,
              const unsigned short* __restrict__ w1bf,  // bf16 W1 (if USE_WS)
              const float* __restrict__ w1f,            // fp32 W1 (fallback)
              const float* __restrict__ b1,
              const float* __restrict__ w2,
              const float* __restrict__ b2,
              float* __restrict__ out)
{
  // mem1 state: plane p = rt*2+ct, per-thread f32x4 slot -> 8*1024*16 B = 128 KB
  __shared__ __align__(16) float mem_lds[8][1024][4];
  __shared__ float red[2][64][17];   // double-buffered by t&1 -> no trailing barrier

  const int tid  = threadIdx.x;
  const int lane = tid & 63;
  const int wave = tid >> 6;          // 0..15
  const int l15  = lane & 15;
  const int lq   = lane >> 4;         // 0..3
  const long b0  = (long)blockIdx.x * 64;
  const int h0   = wave * 32;         // 32 h-cols per wave (2 col-tiles of 16)

  float w2l[2], b1l[2];
#pragma unroll
  for (int ct = 0; ct < 2; ++ct) {
    int h = h0 + ct * 16 + l15;
    w2l[ct] = w2[h];
    b1l[ct] = b1[h];
  }
  const float bias2 = b2[0];

  // zero-init mem1 planes (own slot each; consumed by same thread only)
#pragma unroll
  for (int p = 0; p < 8; ++p) {
    f32x4 z = {0.f, 0.f, 0.f, 0.f};
    *reinterpret_cast<f32x4*>(&mem_lds[p][tid][0]) = z;
  }

  float mem2 = 0.f, spksum = 0.f;   // per-thread redundant (16 replicas per row)

  // A-frag bases: row = rt*16 + l15, k-base = lq*8; advance by 256 floats per t.
  const float* xr0 = x + (b0 + 0  + l15) * 2560 + lq * 8;
  const float* xr1 = x + (b0 + 16 + l15) * 2560 + lq * 8;
  const float* xr2 = x + (b0 + 32 + l15) * 2560 + lq * 8;
  const float* xr3 = x + (b0 + 48 + l15) * 2560 + lq * 8;

  // W1 fragment bases (bf16 path): h = h0 + ct*16 + l15, k-base = lq*8
  const unsigned short* wb0 = w1bf + (h0 + 0  + l15) * 256 + lq * 8;
  const unsigned short* wb1 = w1bf + (h0 + 16 + l15) * 256 + lq * 8;
  const float* wf0 = w1f + (h0 + 0  + l15) * 256 + lq * 8;
  const float* wf1 = w1f + (h0 + 16 + l15) * 256 + lq * 8;

#pragma unroll 1
  for (int t = 0; t < 10; ++t) {
    f32x4 acc[4][2];
#pragma unroll
    for (int rt = 0; rt < 4; ++rt)
#pragma unroll
      for (int ct = 0; ct < 2; ++ct) {
        f32x4 c = { b1l[ct], b1l[ct], b1l[ct], b1l[ct] };
        acc[rt][ct] = c;
      }

    // ---- GEMM: A-frags direct from global (immediate offsets kk*128 floats -> kk*512 B),
    //      B-frags from L2-resident bf16 W1 ----
#pragma unroll
    for (int kk = 0; kk < 8; ++kk) {
      short8 a[4], bfr[2];
      a[0] = load_a_frag(xr0 + kk * 32);
      a[1] = load_a_frag(xr1 + kk * 32);
      a[2] = load_a_frag(xr2 + kk * 32);
      a[3] = load_a_frag(xr3 + kk * 32);
      if constexpr (USE_WS) {
        bfr[0] = *reinterpret_cast<const short8*>(wb0 + kk * 32);
        bfr[1] = *reinterpret_cast<const short8*>(wb1 + kk * 32);
      } else {
        bfr[0] = load_a_frag(wf0 + kk * 32);
        bfr[1] = load_a_frag(wf1 + kk * 32);
      }
#pragma unroll
      for (int rt = 0; rt < 4; ++rt)
#pragma unroll
        for (int ct = 0; ct < 2; ++ct)
          acc[rt][ct] = __builtin_amdgcn_mfma_f32_16x16x32_bf16(a[rt], bfr[ct], acc[rt][ct], 0, 0, 0);
    }
    xr0 += 256; xr1 += 256; xr2 += 256; xr3 += 256;   // advance to next t

    // ---- LIF1 (mem1 in LDS) + partial W2 dot; reduce per rt ----
#pragma unroll
    for (int rt = 0; rt < 4; ++rt) {
      float pr[4] = {0.f, 0.f, 0.f, 0.f};
#pragma unroll
      for (int ct = 0; ct < 2; ++ct) {
        f32x4* slot = reinterpret_cast<f32x4*>(&mem_lds[rt * 2 + ct][tid][0]);
        f32x4 mv = *slot;
#pragma unroll
        for (int e = 0; e < 4; ++e) {
          float m   = fmaf(mv[e], 0.9f, acc[rt][ct][e]);   // beta*mem + cur1
          float spk = fast_sigmoid(fmaf(m, 10.f, -10.f));  // sigmoid(10*(m-1))
          mv[e] = m - spk;
          pr[e] = fmaf(spk, w2l[ct], pr[e]);
        }
        *slot = mv;
      }
#pragma unroll
      for (int e = 0; e < 4; ++e) {
        float v = pr[e];
        v += __shfl_xor(v, 1);
        v += __shfl_xor(v, 2);
        v += __shfl_xor(v, 4);
        v += __shfl_xor(v, 8);
        if (l15 == 0) red[t & 1][rt * 16 + lq * 4 + e][wave] = v;
      }
    }
    __syncthreads();   // the ONLY barrier per t: red ready for LIF2

    // ---- LIF2, redundant on all threads (row = lane). red is double-buffered, and a
    //      wave can't reach t+2's red[t&1] write without all threads passing t+1's
    //      barrier, which is after this read. ----
    {
      float c2 = bias2;
#pragma unroll
      for (int w = 0; w < 16; ++w) c2 += red[t & 1][lane][w];
      float m   = fmaf(mem2, 0.9f, c2);
      float spk = fast_sigmoid(fmaf(m, 10.f, -10.f));
      mem2   = m - spk;
      spksum += spk;
    }
  }

  if (tid < 64) {
    float y = fast_sigmoid(spksum * 0.1f);
    out[b0 + tid] = y;                      // FLOAT32 output
  }
}

extern "C" void kernel_launch(void* const* d_in, const int* in_sizes, int n_in,
                              void* d_out, int out_size, void* d_ws, size_t ws_size,
                              hipStream_t stream) {
  const float* x  = (const float*)d_in[0];
  const float* W1 = (const float*)d_in[1];
  const float* b1 = (const float*)d_in[2];
  const float* W2 = (const float*)d_in[3];
  const float* b2 = (const float*)d_in[4];
  float* out = (float*)d_out;
  (void)in_sizes; (void)n_in;

  const int grid = out_size / 64;   // out_size == B == 32768 -> 512 blocks

  if (ws_size >= 512 * 256 * sizeof(unsigned short)) {
    unsigned short* w1bf = (unsigned short*)d_ws;   // 256 KB
    w1_to_bf16<<<128, 256, 0, stream>>>(W1, w1bf);
    snn_main<true><<<grid, 1024, 0, stream>>>(x, w1bf, W1, b1, W2, b2, out);
  } else {
    snn_main<false><<<grid, 1024, 0, stream>>>(x, nullptr, W1, b1, W2, b2, out);
  }
}

// Round 12
// 239.839 us; speedup vs baseline: 3.1607x; 3.1607x over previous
//
#include <hip/hip_runtime.h>
#include <hip/hip_bf16.h>

// FraudSNN fused kernel: GEMM (bf16 MFMA) + LIF recurrence, T=10, F=256, H=512.
// R12: synthesis. R11 proved direct-global frag loads die of MLP starvation at the
// immovable 64-VGPR budget -> back to LDS bulk staging (R7 geometry, the only
// spill-free config: VGPR 60, WRITE 128B). Add R8's overlap without its spill source:
//  - xt double-buffered: ds_writes overlap MFMA; pf loads covered by a full MFMA phase
//  - pf = 4 regs (cvt fp32->bf16 at load time, keep packed uint2)
//  - mem1: 7 planes in LDS + plane7 in regs (frees 16KB LDS for xt dbuf)
//  - 3 barriers/t (R7: 5, R8: 4); redundant all-thread LIF2; single red buffer
// LDS 152.8 KB; persistent live ~53 regs < 64.

typedef short short8 __attribute__((ext_vector_type(8)));
typedef float f32x4 __attribute__((ext_vector_type(4)));

__device__ __forceinline__ unsigned short bfbits(float f) {
  union { __hip_bfloat16 h; unsigned short u; } c;
  c.h = __float2bfloat16(f);   // hardware RNE
  return c.u;
}

__device__ __forceinline__ unsigned int bfpack(float a, float b) {
  return (unsigned int)bfbits(a) | ((unsigned int)bfbits(b) << 16);
}

__device__ __forceinline__ float fast_sigmoid(float z) {
  float e = __expf(-z);
  return __builtin_amdgcn_rcpf(1.0f + e);
}

__global__ void w1_to_bf16(const float* __restrict__ w1, unsigned short* __restrict__ o) {
  int i = blockIdx.x * 256 + threadIdx.x;      // 32768 float4s = 131072 floats
  float4 v = reinterpret_cast<const float4*>(w1)[i];
  reinterpret_cast<uint2*>(o)[i] = make_uint2(bfpack(v.x, v.y), bfpack(v.z, v.w));
}

__device__ __forceinline__ short8 cvt_frag(const float* p) {
  const float4 v0 = *reinterpret_cast<const float4*>(p);
  const float4 v1 = *reinterpret_cast<const float4*>(p + 4);
  union { unsigned int u[4]; short8 s; } cv;
  cv.u[0] = bfpack(v0.x, v0.y);
  cv.u[1] = bfpack(v0.z, v0.w);
  cv.u[2] = bfpack(v1.x, v1.y);
  cv.u[3] = bfpack(v1.z, v1.w);
  return cv.s;
}

// 1024 threads = 16 waves. Block: 64 batch rows; wave w owns 64 rows x h in [w*32, w*32+32).
template <bool USE_WS>
__global__
__attribute__((amdgpu_flat_work_group_size(1024, 1024)))
void snn_main(const float* __restrict__ x,
              const unsigned short* __restrict__ w1bf,  // bf16 W1 (if USE_WS)
              const float* __restrict__ w1f,            // fp32 W1 (fallback)
              const float* __restrict__ b1,
              const float* __restrict__ w2,
              const float* __restrict__ b2,
              float* __restrict__ out)
{
  // mem1 planes 0..6 in LDS (per-thread f32x4 slots, proven 0-conflict); plane 7 in regs
  __shared__ __align__(16) float mem_lds[7][1024][4];      // 114,688 B
  __shared__ __align__(16) unsigned short xt[2][64][132];  // dbuf k-half staging, 33,792 B
  __shared__ float red[64][17];                            // 4,352 B   (total 152,832 B)

  const int tid  = threadIdx.x;
  const int lane = tid & 63;
  const int wave = tid >> 6;          // 0..15
  const int l15  = lane & 15;
  const int lq   = lane >> 4;         // 0..3
  const long b0  = (long)blockIdx.x * 64;
  const int h0   = wave * 32;         // 32 h-cols per wave (2 col-tiles of 16)

  float w2l[2], b1l[2];
#pragma unroll
  for (int ct = 0; ct < 2; ++ct) {
    int h = h0 + ct * 16 + l15;
    w2l[ct] = w2[h];
    b1l[ct] = b1[h];
  }
  const float bias2 = b2[0];

  // init mem1: planes 0..6 in LDS (own slot -> no barrier needed), plane 7 in regs
#pragma unroll
  for (int p = 0; p < 7; ++p) {
    f32x4 z = {0.f, 0.f, 0.f, 0.f};
    *reinterpret_cast<f32x4*>(&mem_lds[p][tid][0]) = z;
  }
  f32x4 m7 = {0.f, 0.f, 0.f, 0.f};

  float mem2 = 0.f, spksum = 0.f;   // per-thread redundant (16 replicas per row)

  // staging geometry: thread -> row sr, float4 col sc; loads 2 float4 per 128-col half
  const int sr = tid >> 4;            // 0..63
  const int sc = tid & 15;            // 0..15
  const float* xrow = x + (b0 + sr) * 2560;   // + t*256 + half*128 + {sc*4, sc*4+64}

  // W1 fragment base ptrs
  const unsigned short* wb0 = w1bf + (h0 + l15) * 256 + lq * 8;
  const unsigned short* wb1 = wb0 + 16 * 256;
  const float* wf0 = w1f + (h0 + l15) * 256 + lq * 8;
  const float* wf1 = wf0 + 16 * 256;

  // prologue: load+cvt half0 of t=0  (pf = 4 VGPRs)
  uint2 pfa, pfb;
  {
    const float4 v0 = *reinterpret_cast<const float4*>(xrow + sc * 4);
    const float4 v1 = *reinterpret_cast<const float4*>(xrow + sc * 4 + 64);
    pfa = make_uint2(bfpack(v0.x, v0.y), bfpack(v0.z, v0.w));
    pfb = make_uint2(bfpack(v1.x, v1.y), bfpack(v1.z, v1.w));
  }

#pragma unroll 1
  for (int t = 0; t < 10; ++t) {
    // ---- A: write half0 -> xt[0]; load+cvt half1 of t ----
    *reinterpret_cast<uint2*>(&xt[0][sr][sc * 4]) = pfa;
    *reinterpret_cast<uint2*>(&xt[0][sr][sc * 4 + 64]) = pfb;
    {
      const float4 v0 = *reinterpret_cast<const float4*>(xrow + t * 256 + 128 + sc * 4);
      const float4 v1 = *reinterpret_cast<const float4*>(xrow + t * 256 + 128 + sc * 4 + 64);
      pfa = make_uint2(bfpack(v0.x, v0.y), bfpack(v0.z, v0.w));
      pfb = make_uint2(bfpack(v1.x, v1.y), bfpack(v1.z, v1.w));
    }
    __syncthreads();   // bar1: xt[0] ready

    f32x4 acc[4][2];
#pragma unroll
    for (int rt = 0; rt < 4; ++rt)
#pragma unroll
      for (int ct = 0; ct < 2; ++ct) {
        f32x4 c = { b1l[ct], b1l[ct], b1l[ct], b1l[ct] };
        acc[rt][ct] = c;
      }

    // ---- B: MFMA kk 0..3 from xt[0]; then write half1 -> xt[1]; load half0(t+1) ----
#pragma unroll
    for (int kk = 0; kk < 4; ++kk) {
      short8 a[4], bfr[2];
#pragma unroll
      for (int rt = 0; rt < 4; ++rt)
        a[rt] = *reinterpret_cast<const short8*>(&xt[0][rt * 16 + l15][kk * 32 + lq * 8]);
      if constexpr (USE_WS) {
        bfr[0] = *reinterpret_cast<const short8*>(wb0 + kk * 32);
        bfr[1] = *reinterpret_cast<const short8*>(wb1 + kk * 32);
      } else {
        bfr[0] = cvt_frag(wf0 + kk * 32);
        bfr[1] = cvt_frag(wf1 + kk * 32);
      }
#pragma unroll
      for (int rt = 0; rt < 4; ++rt)
#pragma unroll
        for (int ct = 0; ct < 2; ++ct)
          acc[rt][ct] = __builtin_amdgcn_mfma_f32_16x16x32_bf16(a[rt], bfr[ct], acc[rt][ct], 0, 0, 0);
    }
    *reinterpret_cast<uint2*>(&xt[1][sr][sc * 4]) = pfa;
    *reinterpret_cast<uint2*>(&xt[1][sr][sc * 4 + 64]) = pfb;
    {
      const int tn = (t < 9) ? t + 1 : 9;   // tail: harmless re-read
      const float4 v0 = *reinterpret_cast<const float4*>(xrow + tn * 256 + sc * 4);
      const float4 v1 = *reinterpret_cast<const float4*>(xrow + tn * 256 + sc * 4 + 64);
      pfa = make_uint2(bfpack(v0.x, v0.y), bfpack(v0.z, v0.w));
      pfb = make_uint2(bfpack(v1.x, v1.y), bfpack(v1.z, v1.w));
    }
    __syncthreads();   // bar2: xt[1] ready

    // ---- E: MFMA kk 4..7 from xt[1] ----
#pragma unroll
    for (int kkL = 0; kkL < 4; ++kkL) {
      const int kk = 4 + kkL;
      short8 a[4], bfr[2];
#pragma unroll
      for (int rt = 0; rt < 4; ++rt)
        a[rt] = *reinterpret_cast<const short8*>(&xt[1][rt * 16 + l15][kkL * 32 + lq * 8]);
      if constexpr (USE_WS) {
        bfr[0] = *reinterpret_cast<const short8*>(wb0 + kk * 32);
        bfr[1] = *reinterpret_cast<const short8*>(wb1 + kk * 32);
      } else {
        bfr[0] = cvt_frag(wf0 + kk * 32);
        bfr[1] = cvt_frag(wf1 + kk * 32);
      }
#pragma unroll
      for (int rt = 0; rt < 4; ++rt)
#pragma unroll
        for (int ct = 0; ct < 2; ++ct)
          acc[rt][ct] = __builtin_amdgcn_mfma_f32_16x16x32_bf16(a[rt], bfr[ct], acc[rt][ct], 0, 0, 0);
    }

    // ---- F: LIF1 + partial W2 dot (planes 0..6 LDS, plane 7 regs); reduce per rt ----
#pragma unroll
    for (int rt = 0; rt < 4; ++rt) {
      float pr[4] = {0.f, 0.f, 0.f, 0.f};
#pragma unroll
      for (int ct = 0; ct < 2; ++ct) {
        const int p = rt * 2 + ct;
        f32x4 mv;
        if (p < 7) mv = *reinterpret_cast<f32x4*>(&mem_lds[p][tid][0]);
        else       mv = m7;
#pragma unroll
        for (int e = 0; e < 4; ++e) {
          float m   = fmaf(mv[e], 0.9f, acc[rt][ct][e]);   // beta*mem + cur1
          float spk = fast_sigmoid(fmaf(m, 10.f, -10.f));  // sigmoid(10*(m-1))
          mv[e] = m - spk;
          pr[e] = fmaf(spk, w2l[ct], pr[e]);
        }
        if (p < 7) *reinterpret_cast<f32x4*>(&mem_lds[p][tid][0]) = mv;
        else       m7 = mv;
      }
#pragma unroll
      for (int e = 0; e < 4; ++e) {
        float v = pr[e];
        v += __shfl_xor(v, 1);
        v += __shfl_xor(v, 2);
        v += __shfl_xor(v, 4);
        v += __shfl_xor(v, 8);
        if (l15 == 0) red[rt * 16 + lq * 4 + e][wave] = v;
      }
    }
    __syncthreads();   // bar3: red ready

    // ---- H: LIF2, redundant on all threads (row = lane). Next red write is F(t+1),
    //      behind bar1(t+1) and bar2(t+1) -> single buffer is safe. ----
    {
      float c2 = bias2;
#pragma unroll
      for (int w = 0; w < 16; ++w) c2 += red[lane][w];
      float m   = fmaf(mem2, 0.9f, c2);
      float spk = fast_sigmoid(fmaf(m, 10.f, -10.f));
      mem2   = m - spk;
      spksum += spk;
    }
  }

  if (tid < 64) {
    float y = fast_sigmoid(spksum * 0.1f);
    out[b0 + tid] = y;                      // FLOAT32 output
  }
}

extern "C" void kernel_launch(void* const* d_in, const int* in_sizes, int n_in,
                              void* d_out, int out_size, void* d_ws, size_t ws_size,
                              hipStream_t stream) {
  const float* x  = (const float*)d_in[0];
  const float* W1 = (const float*)d_in[1];
  const float* b1 = (const float*)d_in[2];
  const float* W2 = (const float*)d_in[3];
  const float* b2 = (const float*)d_in[4];
  float* out = (float*)d_out;
  (void)in_sizes; (void)n_in;

  const int grid = out_size / 64;   // out_size == B == 32768 -> 512 blocks

  if (ws_size >= 512 * 256 * sizeof(unsigned short)) {
    unsigned short* w1bf = (unsigned short*)d_ws;   // 256 KB
    w1_to_bf16<<<128, 256, 0, stream>>>(W1, w1bf);
    snn_main<true><<<grid, 1024, 0, stream>>>(x, w1bf, W1, b1, W2, b2, out);
  } else {
    snn_main<false><<<grid, 1024, 0, stream>>>(x, nullptr, W1, b1, W2, b2, out);
  }
}